// Round 13
// baseline (509.677 us; speedup 1.0000x reference)
//
#include <hip/hip_runtime.h>
#include <hip/hip_bf16.h>

#define T_TOK 2048
#define HIDN  4096
#define NH    32
#define HD    192
#define QLORA 1536
#define OLORA 512
#define NG    4
#define NFUSE 1728   // QLORA + HD (fused GEMM1+GEMM3 output width)

typedef unsigned short u16;
typedef __attribute__((ext_vector_type(8))) short short8;
typedef __attribute__((ext_vector_type(4))) short short4v;
typedef __attribute__((ext_vector_type(4))) float f32x4;

__device__ __forceinline__ float b2f(u16 u) {
  union { unsigned int u; float f; } x; x.u = ((unsigned int)u) << 16; return x.f;
}
__device__ __forceinline__ u16 f2b(float f) {
  union { float f; unsigned int u; } x; x.f = f;
  unsigned int r = x.u + 0x7fff + ((x.u >> 16) & 1);
  return (u16)(r >> 16);
}

#define GLOAD16(gp, lp) __builtin_amdgcn_global_load_lds( \
    (const __attribute__((address_space(1))) unsigned int*)(gp), \
    (__attribute__((address_space(3))) unsigned int*)(lp), 16, 0, 0)
#define SCHEDB() __builtin_amdgcn_sched_barrier(0)
#define SBAR()   __builtin_amdgcn_s_barrier()

// ---------------- fused cast f32 -> bf16 (6 segments, one launch) ----------
__device__ __forceinline__ void cast_seg(const float* __restrict__ src,
                                         u16* __restrict__ dst, long n4,
                                         long idx, long stride) {
  for (long j = idx; j < n4; j += stride) {
    float4 v = *reinterpret_cast<const float4*>(src + j * 4);
    short4v o;
    o[0] = (short)f2b(v.x); o[1] = (short)f2b(v.y);
    o[2] = (short)f2b(v.z); o[3] = (short)f2b(v.w);
    *reinterpret_cast<short4v*>(dst + j * 4) = o;
  }
}

__global__ __launch_bounds__(256)
void cast6(const float* s0, u16* d0, long n0, const float* s1, u16* d1, long n1,
           const float* s2, u16* d2, long n2, const float* s3, u16* d3, long n3,
           const float* s4, u16* d4, long n4c, const float* s5, u16* d5, long n5) {
  long idx = (long)blockIdx.x * blockDim.x + threadIdx.x;
  long stride = (long)gridDim.x * blockDim.x;
  cast_seg(s0, d0, n0, idx, stride);
  cast_seg(s1, d1, n1, idx, stride);
  cast_seg(s2, d2, n2, idx, stride);
  cast_seg(s3, d3, n3, idx, stride);
  cast_seg(s4, d4, n4c, idx, stride);
  cast_seg(s5, d5, n5, idx, stride);
}

// ---------------- GEMM: C[M,N] = A[M,K] * B[N,K]^T --------------------------
// 128x128 tile, BK=32, 4 waves. Double-buffered LDS, counted vmcnt(4),
// raw s_barrier. XCD-aware bijective block swizzle (valid: nwg % 8 == 0).
// OM: 0 = bf16 store, 1 = f32 store
template <int OM>
__global__ __launch_bounds__(256)
void gemm_bt(const u16* __restrict__ A, const u16* __restrict__ B,
             void* __restrict__ Cout, int M, int N, int K,
             int lda, int ldb, int ldc,
             long a_goff, long b_goff, long c_goff) {
  A += (long)blockIdx.z * a_goff;
  B += (long)blockIdx.z * b_goff;
  __shared__ u16 As[2][128 * 32];
  __shared__ u16 Bs[2][128 * 32];
  const int tid = threadIdx.x;
  const int lane = tid & 63;
  const int wave = tid >> 6;
  const int lg = lane >> 4, lr = lane & 15;
  const int wm = (wave >> 1) * 64, wn = (wave & 1) * 64;

  // XCD swizzle on the (x,y) plane
  int bx = blockIdx.x, by = blockIdx.y;
  {
    int nx = gridDim.x, nwg = nx * gridDim.y;
    if ((nwg & 7) == 0) {
      int lin = by * nx + bx;
      int swz = (lin & 7) * (nwg >> 3) + (lin >> 3);
      bx = swz % nx; by = swz / nx;
    }
  }
  const int m0 = bx * 128, n0 = by * 128;

  const int i0 = tid, i1 = tid + 256;
  const int ra0 = i0 >> 2, ka0 = (i0 & 3) * 8;
  const int ra1 = i1 >> 2, ka1 = (i1 & 3) * 8;
  const u16* pA0 = A + (long)(m0 + ra0) * lda + ka0;
  const u16* pA1 = A + (long)(m0 + ra1) * lda + ka1;
  int rb0 = n0 + ra0; if (rb0 > N - 1) rb0 = N - 1;
  int rb1 = n0 + ra1; if (rb1 > N - 1) rb1 = N - 1;
  const u16* pB0 = B + (long)rb0 * ldb + ka0;
  const u16* pB1 = B + (long)rb1 * ldb + ka1;
  const int woff = wave * 1024;

  f32x4 acc[4][4];
#pragma unroll
  for (int a = 0; a < 4; a++)
#pragma unroll
    for (int b = 0; b < 4; b++) acc[a][b] = f32x4{0.f, 0.f, 0.f, 0.f};

  // prologue: stage tile 0 into buf 0
  GLOAD16(pA0, (char*)As + woff);
  GLOAD16(pA1, (char*)As + 4096 + woff);
  GLOAD16(pB0, (char*)Bs + woff);
  GLOAD16(pB1, (char*)Bs + 4096 + woff);

  const int nk = K >> 5;
  int buf = 0;
  for (int kk = 0; kk < nk; ++kk) {
    const int kn = (kk + 1 < nk) ? (kk + 1) * 32 : kk * 32;
    {
      char* dA = (char*)As + (buf ^ 1) * 8192 + woff;
      char* dB = (char*)Bs + (buf ^ 1) * 8192 + woff;
      GLOAD16(pA0 + kn, dA);
      GLOAD16(pA1 + kn, dA + 4096);
      GLOAD16(pB0 + kn, dB);
      GLOAD16(pB1 + kn, dB + 4096);
    }
    asm volatile("s_waitcnt vmcnt(4)" ::: "memory");  // current tile resident
    SCHEDB(); SBAR(); SCHEDB();

    short8 af[4], bf[4];
#pragma unroll
    for (int i = 0; i < 4; i++)
      af[i] = *reinterpret_cast<const short8*>(&As[buf][(wm + i * 16 + lr) * 32 + lg * 8]);
#pragma unroll
    for (int i = 0; i < 4; i++)
      bf[i] = *reinterpret_cast<const short8*>(&Bs[buf][(wn + i * 16 + lr) * 32 + lg * 8]);
#pragma unroll
    for (int mi = 0; mi < 4; mi++)
#pragma unroll
      for (int ni = 0; ni < 4; ni++)
        acc[mi][ni] = __builtin_amdgcn_mfma_f32_16x16x32_bf16(af[mi], bf[ni], acc[mi][ni], 0, 0, 0);

    SCHEDB(); SBAR(); SCHEDB();   // all waves done reading buf
    buf ^= 1;
  }
  asm volatile("s_waitcnt vmcnt(0)" ::: "memory");  // drain dup stage

  const long cbase = (long)blockIdx.z * c_goff;
#pragma unroll
  for (int mi = 0; mi < 4; mi++) {
#pragma unroll
    for (int ni = 0; ni < 4; ni++) {
      int col = n0 + wn + ni * 16 + lr;
      if (col < N) {
#pragma unroll
        for (int i = 0; i < 4; i++) {
          int row = m0 + wm + mi * 16 + lg * 4 + i;
          float v = acc[mi][ni][i];
          if constexpr (OM == 0)
            reinterpret_cast<u16*>(Cout)[cbase + (long)row * ldc + col] = f2b(v);
          else
            reinterpret_cast<float*>(Cout)[cbase + (long)row * ldc + col] = v;
        }
      }
    }
  }
}

// ---------------- fused RMSNorm(first 1536 cols) + kv-norm+RoPE ------------
// One block per token row. Threads 0..255 rmsnorm cols [0,1536) in-place;
// then wave 0 processes tail cols [1536,1728) -> kvb + kvT (disjoint cols).
__global__ __launch_bounds__(256)
void rmsnorm_kv(u16* __restrict__ buf, const float* __restrict__ w,
                u16* __restrict__ kvb, u16* __restrict__ kvT,
                const float* __restrict__ kvnw, const int* __restrict__ pos,
                const float* __restrict__ rc, const float* __restrict__ rs) {
  const int row = blockIdx.x;
  u16* p = buf + (long)row * NFUSE;
  const int tid = threadIdx.x;
  float v[6];
  float ss = 0.f;
#pragma unroll
  for (int j = 0; j < 6; j++) { v[j] = b2f(p[tid + j * 256]); ss += v[j] * v[j]; }
#pragma unroll
  for (int m = 1; m < 64; m <<= 1) ss += __shfl_xor(ss, m);
  __shared__ float red[4];
  if ((tid & 63) == 0) red[tid >> 6] = ss;
  __syncthreads();
  ss = red[0] + red[1] + red[2] + red[3];
  float rinv = rsqrtf(ss * (1.0f / QLORA) + 1e-6f);
#pragma unroll
  for (int j = 0; j < 6; j++) p[tid + j * 256] = f2b(v[j] * rinv * w[tid + j * 256]);

  if (tid < 64) {  // wave 0: kv tail norm + rope
    const u16* src = p + QLORA;
    const int lane = tid;
    float v0 = b2f(src[lane]), v1 = b2f(src[lane + 64]), v2 = b2f(src[lane + 128]);
    float s2 = v0 * v0 + v1 * v1 + v2 * v2;
#pragma unroll
    for (int m = 1; m < 64; m <<= 1) s2 += __shfl_xor(s2, m);
    float ri = rsqrtf(s2 * (1.0f / HD) + 1e-6f);
    v0 *= ri * kvnw[lane]; v1 *= ri * kvnw[lane + 64]; v2 *= ri * kvnw[lane + 128];
    float partner = __shfl_xor(v2, 1);
    int pp = pos[row];
    int j = lane >> 1;
    float c = rc[pp * 32 + j], s = rs[pp * 32 + j];
    float r = ((lane & 1) == 0) ? (v2 * c - partner * s) : (partner * s + v2 * c);
    u16 o0 = f2b(v0), o1 = f2b(v1), o2 = f2b(r);
    u16* kp = kvb + (long)row * HD;
    kp[lane] = o0; kp[lane + 64] = o1; kp[lane + 128] = o2;
    kvT[(long)lane * T_TOK + row] = o0;
    kvT[(long)(lane + 64) * T_TOK + row] = o1;
    kvT[(long)(lane + 128) * T_TOK + row] = o2;
  }
}

// ---------------- per-(t,h) RMSNorm (unweighted) + RoPE, in-place ----------
// Output pre-scaled by 192^-0.5 * log2(e): attention runs in exp2 domain.
__global__ __launch_bounds__(256)
void qnorm_rope(u16* __restrict__ q, const int* __restrict__ pos,
                const float* __restrict__ rc, const float* __restrict__ rs) {
  const int t = blockIdx.x, h = blockIdx.y * 4 + (threadIdx.x >> 6);
  u16* p = q + (long)t * (NH * HD) + h * HD;
  const int lane = threadIdx.x & 63;
  const float QS = 0.07216878364870323f * 1.4426950408889634f;
  float v0 = b2f(p[lane]), v1 = b2f(p[lane + 64]), v2 = b2f(p[lane + 128]);
  float ss = v0 * v0 + v1 * v1 + v2 * v2;
#pragma unroll
  for (int m = 1; m < 64; m <<= 1) ss += __shfl_xor(ss, m);
  float rinv = rsqrtf(ss * (1.0f / HD) + 1e-6f);
  v0 *= rinv; v1 *= rinv; v2 *= rinv;
  float partner = __shfl_xor(v2, 1);
  int pp = pos[t];
  int j = lane >> 1;
  float c = rc[pp * 32 + j], s = rs[pp * 32 + j];
  float r = ((lane & 1) == 0) ? (v2 * c - partner * s) : (partner * s + v2 * c);
  p[lane] = f2b(v0 * QS); p[lane + 64] = f2b(v1 * QS); p[lane + 128] = f2b(r * QS);
}

// ---------------- flash attention: K LDS-staged, V direct from L1/L2 -------
// block = 512 thr = 8 waves = 8 heads x same 16 q rows. KVBLK=64.
// K double-buffered via global_load_lds (counted vmcnt(3)); V-fragments read
// directly from global kvT (24 KB tile fits L1; 8 waves re-read it hot).
// LDS 65.6 KB -> 2 blocks/CU (16 waves) so barrier drains overlap.
// Each block does two q-tiles (127-bx, bx) -> uniform work; grid 64 x 4.
// Reduction-free exp2 softmax; denominator via ones-MFMA.
__global__ __launch_bounds__(512)
void attn(const u16* __restrict__ q, const u16* __restrict__ kv,
          const u16* __restrict__ kvT, const float* __restrict__ sink,
          u16* __restrict__ out) {
  __shared__ u16 Ks[2][64 * 192];   // 48 KB
  __shared__ u16 P[8][16 * 68];     // 17 KB, per-wave private
  const int tid = threadIdx.x;
  const int wave = tid >> 6, lane = tid & 63;
  const int lg = lane >> 4, lr = lane & 15;
  const int h = blockIdx.y * 8 + wave;
  u16* Pw = P[wave];

  // K staging map: 3 chunks (16B) per thread, pre-swizzled global source
  int krow[3], koff[3];
#pragma unroll
  for (int j = 0; j < 3; j++) {
    int s = tid + j * 512;
    int rk = s / 24, ck = s - rk * 24;   // 24 chunks per 192-elem row
    krow[j] = rk; koff[j] = (ck ^ (rk & 7)) * 8;
  }
  const float skw = exp2f(sink[h] * 1.4426950408889634f);  // denom sink term
  short8 onesf;
#pragma unroll
  for (int k = 0; k < 8; k++) onesf[k] = (short)0x3F80;    // bf16 1.0 x8
  int buf = 0;

  for (int pass = 0; pass < 2; ++pass) {
    const int qb = pass ? (int)blockIdx.x : (127 - (int)blockIdx.x);
    const int q0 = qb * 16;
    const int s_end = q0 + 16;
    const int nt = (s_end + 63) >> 6;

    short8 qf[6];
#pragma unroll
    for (int c = 0; c < 6; c++)
      qf[c] = *reinterpret_cast<const short8*>(
          q + (long)(q0 + lr) * (NH * HD) + h * HD + c * 32 + lg * 8);

    f32x4 acc[12], accS;
#pragma unroll
    for (int c = 0; c < 12; c++) acc[c] = f32x4{0.f, 0.f, 0.f, 0.f};
    accS = f32x4{0.f, 0.f, 0.f, 0.f};

    // prologue: stage K tile 0 into buf
    {
      char* dK = (char*)Ks[buf];
#pragma unroll
      for (int j = 0; j < 3; j++)
        GLOAD16(kv + (long)krow[j] * HD + koff[j], dK + (tid + j * 512) * 16);
    }

    for (int t = 0; t < nt; ++t) {
      const int s0 = t * 64;
      const int sn = (t + 1 < nt) ? s0 + 64 : s0;  // dup-stage on last iter
      {
        char* dK = (char*)Ks[buf ^ 1];
#pragma unroll
        for (int j = 0; j < 3; j++)
          GLOAD16(kv + (long)(sn + krow[j]) * HD + koff[j], dK + (tid + j * 512) * 16);
      }
      asm volatile("s_waitcnt vmcnt(3)" ::: "memory");  // K tile t resident
      SCHEDB(); SBAR(); SCHEDB();

      const u16* Kb = Ks[buf];
      f32x4 sc[4];
      __builtin_amdgcn_s_setprio(1);
#pragma unroll
      for (int sub = 0; sub < 4; sub++) {
        int c0 = s0 + sub * 16;
        f32x4 v = f32x4{0.f, 0.f, 0.f, 0.f};
        if (c0 < s_end) {  // uniform across all 8 waves
#pragma unroll
          for (int c = 0; c < 6; c++) {
            short8 kf = *reinterpret_cast<const short8*>(
                &Kb[((sub * 16 + lr) * HD + c * 32 + lg * 8) ^ ((lr & 7) << 3)]);
            v = __builtin_amdgcn_mfma_f32_16x16x32_bf16(qf[c], kf, v, 0, 0, 0);
          }
          int scol = c0 + lr;
#pragma unroll
          for (int i = 0; i < 4; i++) {
            int qrow = q0 + lg * 4 + i;
            v[i] = (scol <= qrow) ? v[i] : -__builtin_inff();
          }
        } else {
#pragma unroll
          for (int i = 0; i < 4; i++) v[i] = -__builtin_inff();
        }
        sc[sub] = v;
      }
      __builtin_amdgcn_s_setprio(0);

      // reduction-free softmax: P = exp2(score), masked -> exp2(-inf) = 0
      float pr[4][4];
#pragma unroll
      for (int sub = 0; sub < 4; sub++)
#pragma unroll
        for (int i = 0; i < 4; i++) pr[sub][i] = exp2f(sc[sub][i]);
#pragma unroll
      for (int sub = 0; sub < 4; sub++)
#pragma unroll
        for (int i = 0; i < 4; i++)
          Pw[(lg * 4 + i) * 68 + sub * 16 + lr] = f2b(pr[sub][i]);
      short8 pf0 = *reinterpret_cast<const short8*>(&Pw[lr * 68 + lg * 8]);
      short8 pf1 = *reinterpret_cast<const short8*>(&Pw[lr * 68 + 32 + lg * 8]);

      __builtin_amdgcn_s_setprio(1);
#pragma unroll
      for (int c = 0; c < 12; c++) {
        short8 vf = *reinterpret_cast<const short8*>(
            kvT + (long)(c * 16 + lr) * T_TOK + s0 + lg * 8);
        acc[c] = __builtin_amdgcn_mfma_f32_16x16x32_bf16(pf0, vf, acc[c], 0, 0, 0);
      }
      accS = __builtin_amdgcn_mfma_f32_16x16x32_bf16(pf0, onesf, accS, 0, 0, 0);
      if (s0 + 32 < s_end) {  // uniform
#pragma unroll
        for (int c = 0; c < 12; c++) {
          short8 vf = *reinterpret_cast<const short8*>(
              kvT + (long)(c * 16 + lr) * T_TOK + s0 + 32 + lg * 8);
          acc[c] = __builtin_amdgcn_mfma_f32_16x16x32_bf16(pf1, vf, acc[c], 0, 0, 0);
        }
        accS = __builtin_amdgcn_mfma_f32_16x16x32_bf16(pf1, onesf, accS, 0, 0, 0);
      }
      __builtin_amdgcn_s_setprio(0);

      SCHEDB(); SBAR(); SCHEDB();  // all waves done reading K buf
      buf ^= 1;
    }

    asm volatile("s_waitcnt vmcnt(0)" ::: "memory");  // drain dup stage
    float rdenom[4];
#pragma unroll
    for (int i = 0; i < 4; i++) rdenom[i] = 1.0f / (skw + accS[i]);
#pragma unroll
    for (int c = 0; c < 12; c++)
#pragma unroll
      for (int i = 0; i < 4; i++) {
        int qrow = q0 + lg * 4 + i;
        out[(long)qrow * (NH * HD) + h * HD + c * 16 + lr] = f2b(acc[c][i] * rdenom[i]);
      }
    SBAR();
  }
}

// ---------------------------------------------------------------------------
extern "C" void kernel_launch(void* const* d_in, const int* in_sizes, int n_in,
                              void* d_out, int out_size, void* d_ws, size_t ws_size,
                              hipStream_t stream) {
  const float* x    = (const float*)d_in[0];
  const int* pos    = (const int*)d_in[1];
  const float* wq_a = (const float*)d_in[2];
  const float* q_nw = (const float*)d_in[3];
  const float* wq_b = (const float*)d_in[4];
  const float* wkv  = (const float*)d_in[5];
  const float* kvnw = (const float*)d_in[6];
  const float* sink = (const float*)d_in[7];
  const float* wo_a = (const float*)d_in[8];
  const float* wo_b = (const float*)d_in[9];
  const float* rcos = (const float*)d_in[10];
  const float* rsin = (const float*)d_in[11];
  float* y = (float*)d_out;

  char* ws = (char*)d_ws;
  size_t off = 0;
  auto alloc = [&](size_t bytes) -> void* {
    void* p = ws + off;
    off += (bytes + 255) & ~(size_t)255;
    return p;
  };
  u16* xb   = (u16*)alloc((size_t)T_TOK * HIDN * 2);
  u16* wqab = (u16*)alloc((size_t)QLORA * HIDN * 2);  // contiguous with wkvb:
  u16* wkvb = (u16*)alloc((size_t)HD * HIDN * 2);     // fused B = [wq_a; wkv]
  u16* wqbb = (u16*)alloc((size_t)NH * HD * QLORA * 2);
  u16* woab = (u16*)alloc((size_t)NG * OLORA * 1536 * 2);
  u16* wobb = (u16*)alloc((size_t)HIDN * NG * OLORA * 2);
  u16* t1f  = (u16*)alloc((size_t)T_TOK * NFUSE * 2);   // [2048][1728]
  u16* qn   = (u16*)alloc((size_t)T_TOK * NH * HD * 2);
  u16* kvb  = (u16*)alloc((size_t)T_TOK * HD * 2);
  u16* kvT  = (u16*)alloc((size_t)HD * T_TOK * 2);
  u16* ao   = (u16*)alloc((size_t)T_TOK * NH * HD * 2);
  u16* olow = (u16*)alloc((size_t)T_TOK * NG * OLORA * 2);

  // one fused cast launch (6 segments)
  hipLaunchKernelGGL(cast6, dim3(1024), dim3(256), 0, stream,
                     x,    xb,   (long)T_TOK * HIDN / 4,
                     wq_a, wqab, (long)QLORA * HIDN / 4,
                     wkv,  wkvb, (long)HD * HIDN / 4,
                     wq_b, wqbb, (long)NH * HD * QLORA / 4,
                     wo_a, woab, (long)NG * OLORA * 1536 / 4,
                     wo_b, wobb, (long)HIDN * NG * OLORA / 4);

  // fused GEMM1+GEMM3: t1f[2048,1728] = xb @ [wq_a; wkv]^T
  hipLaunchKernelGGL((gemm_bt<0>), dim3(16, 14, 1), dim3(256), 0, stream,
                     xb, wqab, (void*)t1f, 2048, NFUSE, 4096, 4096, 4096, NFUSE, 0L, 0L, 0L);
  // fused rmsnorm (q_lora cols) + kv norm/rope (tail cols)
  hipLaunchKernelGGL(rmsnorm_kv, dim3(2048), dim3(256), 0, stream,
                     t1f, q_nw, kvb, kvT, kvnw, pos, rcos, rsin);
  // GEMM2: qn[2048,6144] = t1f[:, :1536] @ wq_b^T
  hipLaunchKernelGGL((gemm_bt<0>), dim3(16, 48, 1), dim3(256), 0, stream,
                     t1f, wqbb, (void*)qn, 2048, 6144, 1536, NFUSE, 1536, 6144, 0L, 0L, 0L);
  hipLaunchKernelGGL(qnorm_rope, dim3(2048, 8), dim3(256), 0, stream, qn, pos, rcos, rsin);
  // attention: 64 paired q-tiles x 4 head-groups = 256 blocks, 512 thr
  hipLaunchKernelGGL(attn, dim3(64, 4), dim3(512), 0, stream, qn, kvb, kvT, sink, ao);
  // GEMM4 (grouped): olow[2048, 4*512] = ao_g @ wo_a_g^T
  hipLaunchKernelGGL((gemm_bt<0>), dim3(16, 4, 4), dim3(256), 0, stream,
                     ao, woab, (void*)olow, 2048, 512, 1536, 6144, 1536, 2048,
                     1536L, (long)512 * 1536, 512L);
  // GEMM5: y[2048,4096] = olow @ wo_b^T (f32 out)
  hipLaunchKernelGGL((gemm_bt<1>), dim3(16, 32, 1), dim3(256), 0, stream,
                     olow, wobb, (void*)y, 2048, 4096, 2048, 2048, 2048, 4096, 0L, 0L, 0L);
}

// Round 14
// 388.581 us; speedup vs baseline: 1.3116x; 1.3116x over previous
//
#include <hip/hip_runtime.h>
#include <hip/hip_bf16.h>

#define T_TOK 2048
#define HIDN  4096
#define NH    32
#define HD    192
#define QLORA 1536
#define OLORA 512
#define NG    4
#define NFUSE 1728   // QLORA + HD (fused GEMM1+GEMM3 output width)

typedef unsigned short u16;
typedef __attribute__((ext_vector_type(8))) short short8;
typedef __attribute__((ext_vector_type(4))) short short4v;
typedef __attribute__((ext_vector_type(4))) float f32x4;

__device__ __forceinline__ float b2f(u16 u) {
  union { unsigned int u; float f; } x; x.u = ((unsigned int)u) << 16; return x.f;
}
__device__ __forceinline__ u16 f2b(float f) {
  union { float f; unsigned int u; } x; x.f = f;
  unsigned int r = x.u + 0x7fff + ((x.u >> 16) & 1);
  return (u16)(r >> 16);
}

#define GLOAD16(gp, lp) __builtin_amdgcn_global_load_lds( \
    (const __attribute__((address_space(1))) unsigned int*)(gp), \
    (__attribute__((address_space(3))) unsigned int*)(lp), 16, 0, 0)
#define SCHEDB() __builtin_amdgcn_sched_barrier(0)
#define SBAR()   __builtin_amdgcn_s_barrier()

// ---------------- fused cast f32 -> bf16 (6 segments, one launch) ----------
__device__ __forceinline__ void cast_seg(const float* __restrict__ src,
                                         u16* __restrict__ dst, long n4,
                                         long idx, long stride) {
  for (long j = idx; j < n4; j += stride) {
    float4 v = *reinterpret_cast<const float4*>(src + j * 4);
    short4v o;
    o[0] = (short)f2b(v.x); o[1] = (short)f2b(v.y);
    o[2] = (short)f2b(v.z); o[3] = (short)f2b(v.w);
    *reinterpret_cast<short4v*>(dst + j * 4) = o;
  }
}

__global__ __launch_bounds__(256)
void cast6(const float* s0, u16* d0, long n0, const float* s1, u16* d1, long n1,
           const float* s2, u16* d2, long n2, const float* s3, u16* d3, long n3,
           const float* s4, u16* d4, long n4c, const float* s5, u16* d5, long n5) {
  long idx = (long)blockIdx.x * blockDim.x + threadIdx.x;
  long stride = (long)gridDim.x * blockDim.x;
  cast_seg(s0, d0, n0, idx, stride);
  cast_seg(s1, d1, n1, idx, stride);
  cast_seg(s2, d2, n2, idx, stride);
  cast_seg(s3, d3, n3, idx, stride);
  cast_seg(s4, d4, n4c, idx, stride);
  cast_seg(s5, d5, n5, idx, stride);
}

// ---------------- GEMM 128x128 (kept for GEMM1 / grouped GEMM4) ------------
// OM: 0 = bf16 store, 1 = f32 store
template <int OM>
__global__ __launch_bounds__(256)
void gemm_bt(const u16* __restrict__ A, const u16* __restrict__ B,
             void* __restrict__ Cout, int M, int N, int K,
             int lda, int ldb, int ldc,
             long a_goff, long b_goff, long c_goff) {
  A += (long)blockIdx.z * a_goff;
  B += (long)blockIdx.z * b_goff;
  __shared__ u16 As[2][128 * 32];
  __shared__ u16 Bs[2][128 * 32];
  const int tid = threadIdx.x;
  const int lane = tid & 63;
  const int wave = tid >> 6;
  const int lg = lane >> 4, lr = lane & 15;
  const int wm = (wave >> 1) * 64, wn = (wave & 1) * 64;

  int bx = blockIdx.x, by = blockIdx.y;
  {
    int nx = gridDim.x, nwg = nx * gridDim.y;
    if ((nwg & 7) == 0) {
      int lin = by * nx + bx;
      int swz = (lin & 7) * (nwg >> 3) + (lin >> 3);
      bx = swz % nx; by = swz / nx;
    }
  }
  const int m0 = bx * 128, n0 = by * 128;

  const int i0 = tid, i1 = tid + 256;
  const int ra0 = i0 >> 2, ka0 = (i0 & 3) * 8;
  const int ra1 = i1 >> 2, ka1 = (i1 & 3) * 8;
  const u16* pA0 = A + (long)(m0 + ra0) * lda + ka0;
  const u16* pA1 = A + (long)(m0 + ra1) * lda + ka1;
  int rb0 = n0 + ra0; if (rb0 > N - 1) rb0 = N - 1;
  int rb1 = n0 + ra1; if (rb1 > N - 1) rb1 = N - 1;
  const u16* pB0 = B + (long)rb0 * ldb + ka0;
  const u16* pB1 = B + (long)rb1 * ldb + ka1;
  const int woff = wave * 1024;

  f32x4 acc[4][4];
#pragma unroll
  for (int a = 0; a < 4; a++)
#pragma unroll
    for (int b = 0; b < 4; b++) acc[a][b] = f32x4{0.f, 0.f, 0.f, 0.f};

  GLOAD16(pA0, (char*)As + woff);
  GLOAD16(pA1, (char*)As + 4096 + woff);
  GLOAD16(pB0, (char*)Bs + woff);
  GLOAD16(pB1, (char*)Bs + 4096 + woff);

  const int nk = K >> 5;
  int buf = 0;
  for (int kk = 0; kk < nk; ++kk) {
    const int kn = (kk + 1 < nk) ? (kk + 1) * 32 : kk * 32;
    {
      char* dA = (char*)As + (buf ^ 1) * 8192 + woff;
      char* dB = (char*)Bs + (buf ^ 1) * 8192 + woff;
      GLOAD16(pA0 + kn, dA);
      GLOAD16(pA1 + kn, dA + 4096);
      GLOAD16(pB0 + kn, dB);
      GLOAD16(pB1 + kn, dB + 4096);
    }
    asm volatile("s_waitcnt vmcnt(4)" ::: "memory");
    SCHEDB(); SBAR(); SCHEDB();

    short8 af[4], bf[4];
#pragma unroll
    for (int i = 0; i < 4; i++)
      af[i] = *reinterpret_cast<const short8*>(&As[buf][(wm + i * 16 + lr) * 32 + lg * 8]);
#pragma unroll
    for (int i = 0; i < 4; i++)
      bf[i] = *reinterpret_cast<const short8*>(&Bs[buf][(wn + i * 16 + lr) * 32 + lg * 8]);
#pragma unroll
    for (int mi = 0; mi < 4; mi++)
#pragma unroll
      for (int ni = 0; ni < 4; ni++)
        acc[mi][ni] = __builtin_amdgcn_mfma_f32_16x16x32_bf16(af[mi], bf[ni], acc[mi][ni], 0, 0, 0);

    SCHEDB(); SBAR(); SCHEDB();
    buf ^= 1;
  }
  asm volatile("s_waitcnt vmcnt(0)" ::: "memory");

  const long cbase = (long)blockIdx.z * c_goff;
#pragma unroll
  for (int mi = 0; mi < 4; mi++) {
#pragma unroll
    for (int ni = 0; ni < 4; ni++) {
      int col = n0 + wn + ni * 16 + lr;
      if (col < N) {
#pragma unroll
        for (int i = 0; i < 4; i++) {
          int row = m0 + wm + mi * 16 + lg * 4 + i;
          float v = acc[mi][ni][i];
          if constexpr (OM == 0)
            reinterpret_cast<u16*>(Cout)[cbase + (long)row * ldc + col] = f2b(v);
          else
            reinterpret_cast<float*>(Cout)[cbase + (long)row * ldc + col] = v;
        }
      }
    }
  }
}

// ---------------- GEMM 256x256, BK=64, 8 waves, phase-pipelined ------------
// Requires M%256==0, N%256==0, K%64==0. One barrier + one (warm) vmcnt(0)
// per 64-K tile; per-tile 4 phases each {stage 1 half-tile of tile k+1,
// 4x ds_read_b128 A-frags, 16 MFMA in setprio}. B-frags cached per tile.
// LDS chunk swizzle cc ^= row&7 on stage-source and read: conflict-free.
// OM: 0 = bf16 store, 1 = f32 store
template <int OM>
__global__ __launch_bounds__(512, 2)
void gemm256(const u16* __restrict__ A, const u16* __restrict__ B,
             void* __restrict__ Cout, int N, int K,
             int lda, int ldb, int ldc) {
  __shared__ u16 As[2 * 2 * 8192];   // [buf][half][128][64]
  __shared__ u16 Bs[2 * 2 * 8192];
  const int tid = threadIdx.x;
  const int lane = tid & 63;
  const int wave = tid >> 6;
  const int lg = lane >> 4, lr = lane & 15;
  const int wm = wave >> 2;          // A half (M 128-half)
  const int wn = wave & 3;           // N quarter (64 cols)
  const int wnh = wn >> 1;           // B half

  int bx = blockIdx.x, by = blockIdx.y;
  {
    int nx = gridDim.x, nwg = nx * gridDim.y;
    int lin = by * nx + bx;
    int swz = (lin & 7) * (nwg >> 3) + (lin >> 3);
    bx = swz % nx; by = swz / nx;
  }
  const int m0 = bx * 256, n0 = by * 256;

  // staging: thread stages chunks c0=tid, c1=tid+512 of each 16KB half-tile.
  // chunk c -> lds byte c*16 (linear, row=c>>3); source col swizzled by row&7.
  const int c0 = tid, c1 = tid + 512;
  const int r0 = c0 >> 3, sc0 = (((c0 & 7) ^ (r0 & 7))) * 8;
  const int r1 = c1 >> 3, sc1 = (((c1 & 7) ^ (r1 & 7))) * 8;
  const u16* pA0 = A + (long)(m0 + r0) * lda + sc0;
  const u16* pA1 = A + (long)(m0 + r1) * lda + sc1;
  const u16* pB0 = B + (long)(n0 + r0) * ldb + sc0;
  const u16* pB1 = B + (long)(n0 + r1) * ldb + sc1;
  const long hA = (long)128 * lda, hB = (long)128 * ldb;
  const int d0 = c0 * 16, d1 = c1 * 16;

#define STG_A(BUF, HALF, KO) do { \
    GLOAD16(pA0 + ((HALF) ? hA : 0) + (KO), (char*)As + ((BUF) * 2 + (HALF)) * 16384 + d0); \
    GLOAD16(pA1 + ((HALF) ? hA : 0) + (KO), (char*)As + ((BUF) * 2 + (HALF)) * 16384 + d1); \
  } while (0)
#define STG_B(BUF, HALF, KO) do { \
    GLOAD16(pB0 + ((HALF) ? hB : 0) + (KO), (char*)Bs + ((BUF) * 2 + (HALF)) * 16384 + d0); \
    GLOAD16(pB1 + ((HALF) ? hB : 0) + (KO), (char*)Bs + ((BUF) * 2 + (HALF)) * 16384 + d1); \
  } while (0)

  f32x4 acc[8][4];
#pragma unroll
  for (int m = 0; m < 8; m++)
#pragma unroll
    for (int n = 0; n < 4; n++) acc[m][n] = f32x4{0.f, 0.f, 0.f, 0.f};

  // read-side chunk offsets (u16 units): element base e=ks*32+lg*8 -> chunk
  // (ks*4+lg), xor row&7 (= lr&7 for all our frag rows)
  const int kx0 = ((0 + lg) ^ (lr & 7)) * 8;
  const int kx1 = ((4 + lg) ^ (lr & 7)) * 8;

  // prologue: tile 0 into buf 0
  STG_A(0, 0, 0); STG_A(0, 1, 0); STG_B(0, 0, 0); STG_B(0, 1, 0);

  const int nk = K >> 6;
  for (int kt = 0; kt < nk; ++kt) {
    asm volatile("s_waitcnt vmcnt(0)" ::: "memory");  // tile kt (issued 1 tile ago)
    SCHEDB(); SBAR(); SCHEDB();
    const int buf = kt & 1, nb = buf ^ 1;
    const long kn = (long)(kt + 1) * 64;
    const bool more = kt + 1 < nk;
    const u16* Ab = As + (buf * 2 + wm) * 8192;
    const u16* Bb = Bs + (buf * 2 + wnh) * 8192;

    // B fragments for the whole tile (register-cached)
    short8 bf[4][2];
#pragma unroll
    for (int n = 0; n < 4; n++) {
      int rb = (wn & 1) * 64 + n * 16 + lr;
      bf[n][0] = *reinterpret_cast<const short8*>(&Bb[rb * 64 + kx0]);
      bf[n][1] = *reinterpret_cast<const short8*>(&Bb[rb * 64 + kx1]);
    }

#define PHASE(PH, STGSTMT) do { \
    if (more) { STGSTMT; } \
    short8 af0a, af0b, af1a, af1b; \
    { int ra = ((PH) * 2 + 0) * 16 + lr; \
      af0a = *reinterpret_cast<const short8*>(&Ab[ra * 64 + kx0]); \
      af0b = *reinterpret_cast<const short8*>(&Ab[ra * 64 + kx1]); } \
    { int ra = ((PH) * 2 + 1) * 16 + lr; \
      af1a = *reinterpret_cast<const short8*>(&Ab[ra * 64 + kx0]); \
      af1b = *reinterpret_cast<const short8*>(&Ab[ra * 64 + kx1]); } \
    SCHEDB(); \
    __builtin_amdgcn_s_setprio(1); \
    _Pragma("unroll") \
    for (int n = 0; n < 4; n++) { \
      acc[(PH) * 2 + 0][n] = __builtin_amdgcn_mfma_f32_16x16x32_bf16(af0a, bf[n][0], acc[(PH) * 2 + 0][n], 0, 0, 0); \
      acc[(PH) * 2 + 0][n] = __builtin_amdgcn_mfma_f32_16x16x32_bf16(af0b, bf[n][1], acc[(PH) * 2 + 0][n], 0, 0, 0); \
      acc[(PH) * 2 + 1][n] = __builtin_amdgcn_mfma_f32_16x16x32_bf16(af1a, bf[n][0], acc[(PH) * 2 + 1][n], 0, 0, 0); \
      acc[(PH) * 2 + 1][n] = __builtin_amdgcn_mfma_f32_16x16x32_bf16(af1b, bf[n][1], acc[(PH) * 2 + 1][n], 0, 0, 0); \
    } \
    __builtin_amdgcn_s_setprio(0); \
    SCHEDB(); \
  } while (0)

    PHASE(0, STG_A(nb, 0, kn));
    PHASE(1, STG_A(nb, 1, kn));
    PHASE(2, STG_B(nb, 0, kn));
    PHASE(3, STG_B(nb, 1, kn));
#undef PHASE
  }

  // epilogue (shapes exact: no guards)
#pragma unroll
  for (int m = 0; m < 8; m++)
#pragma unroll
    for (int n = 0; n < 4; n++)
#pragma unroll
      for (int i = 0; i < 4; i++) {
        int row = m0 + wm * 128 + m * 16 + lg * 4 + i;
        int col = n0 + wn * 64 + n * 16 + lr;
        float v = acc[m][n][i];
        if constexpr (OM == 0)
          reinterpret_cast<u16*>(Cout)[(long)row * ldc + col] = f2b(v);
        else
          reinterpret_cast<float*>(Cout)[(long)row * ldc + col] = v;
      }
#undef STG_A
#undef STG_B
}

// ---------------- fused RMSNorm(first 1536 cols) + kv-norm+RoPE ------------
__global__ __launch_bounds__(256)
void rmsnorm_kv(u16* __restrict__ buf, const float* __restrict__ w,
                u16* __restrict__ kvb, u16* __restrict__ kvT,
                const float* __restrict__ kvnw, const int* __restrict__ pos,
                const float* __restrict__ rc, const float* __restrict__ rs) {
  const int row = blockIdx.x;
  u16* p = buf + (long)row * NFUSE;
  const int tid = threadIdx.x;
  float v[6];
  float ss = 0.f;
#pragma unroll
  for (int j = 0; j < 6; j++) { v[j] = b2f(p[tid + j * 256]); ss += v[j] * v[j]; }
#pragma unroll
  for (int m = 1; m < 64; m <<= 1) ss += __shfl_xor(ss, m);
  __shared__ float red[4];
  if ((tid & 63) == 0) red[tid >> 6] = ss;
  __syncthreads();
  ss = red[0] + red[1] + red[2] + red[3];
  float rinv = rsqrtf(ss * (1.0f / QLORA) + 1e-6f);
#pragma unroll
  for (int j = 0; j < 6; j++) p[tid + j * 256] = f2b(v[j] * rinv * w[tid + j * 256]);

  if (tid < 64) {  // wave 0: kv tail norm + rope
    const u16* src = p + QLORA;
    const int lane = tid;
    float v0 = b2f(src[lane]), v1 = b2f(src[lane + 64]), v2 = b2f(src[lane + 128]);
    float s2 = v0 * v0 + v1 * v1 + v2 * v2;
#pragma unroll
    for (int m = 1; m < 64; m <<= 1) s2 += __shfl_xor(s2, m);
    float ri = rsqrtf(s2 * (1.0f / HD) + 1e-6f);
    v0 *= ri * kvnw[lane]; v1 *= ri * kvnw[lane + 64]; v2 *= ri * kvnw[lane + 128];
    float partner = __shfl_xor(v2, 1);
    int pp = pos[row];
    int j = lane >> 1;
    float c = rc[pp * 32 + j], s = rs[pp * 32 + j];
    float r = ((lane & 1) == 0) ? (v2 * c - partner * s) : (partner * s + v2 * c);
    u16 o0 = f2b(v0), o1 = f2b(v1), o2 = f2b(r);
    u16* kp = kvb + (long)row * HD;
    kp[lane] = o0; kp[lane + 64] = o1; kp[lane + 128] = o2;
    kvT[(long)lane * T_TOK + row] = o0;
    kvT[(long)(lane + 64) * T_TOK + row] = o1;
    kvT[(long)(lane + 128) * T_TOK + row] = o2;
  }
}

// ---------------- per-(t,h) RMSNorm (unweighted) + RoPE, in-place ----------
// Output pre-scaled by 192^-0.5 * log2(e): attention runs in exp2 domain.
__global__ __launch_bounds__(256)
void qnorm_rope(u16* __restrict__ q, const int* __restrict__ pos,
                const float* __restrict__ rc, const float* __restrict__ rs) {
  const int t = blockIdx.x, h = blockIdx.y * 4 + (threadIdx.x >> 6);
  u16* p = q + (long)t * (NH * HD) + h * HD;
  const int lane = threadIdx.x & 63;
  const float QS = 0.07216878364870323f * 1.4426950408889634f;
  float v0 = b2f(p[lane]), v1 = b2f(p[lane + 64]), v2 = b2f(p[lane + 128]);
  float ss = v0 * v0 + v1 * v1 + v2 * v2;
#pragma unroll
  for (int m = 1; m < 64; m <<= 1) ss += __shfl_xor(ss, m);
  float rinv = rsqrtf(ss * (1.0f / HD) + 1e-6f);
  v0 *= rinv; v1 *= rinv; v2 *= rinv;
  float partner = __shfl_xor(v2, 1);
  int pp = pos[t];
  int j = lane >> 1;
  float c = rc[pp * 32 + j], s = rs[pp * 32 + j];
  float r = ((lane & 1) == 0) ? (v2 * c - partner * s) : (partner * s + v2 * c);
  p[lane] = f2b(v0 * QS); p[lane + 64] = f2b(v1 * QS); p[lane + 128] = f2b(r * QS);
}

// ---------------- flash attention (R10 structure, reduction-free softmax) --
__global__ __launch_bounds__(512)
void attn(const u16* __restrict__ q, const u16* __restrict__ kv,
          const u16* __restrict__ kvT, const float* __restrict__ sink,
          u16* __restrict__ out) {
  __shared__ u16 Ks[2][64 * 192];   // 48 KB
  __shared__ u16 Vs[2][192 * 64];   // 48 KB
  __shared__ u16 P[8][16 * 68];     // 17 KB, per-wave private
  const int tid = threadIdx.x;
  const int wave = tid >> 6, lane = tid & 63;
  const int lg = lane >> 4, lr = lane & 15;
  const int h = blockIdx.y * 8 + wave;
  u16* Pw = P[wave];

  int krow[3], koff[3], vrow[3], voff[3];
#pragma unroll
  for (int j = 0; j < 3; j++) {
    int s = tid + j * 512;
    int rk = s / 24, ck = s - rk * 24;   // K: 24 chunks per 192-elem row
    krow[j] = rk; koff[j] = (ck ^ (rk & 7)) * 8;
    int rv = s >> 3, cv = s & 7;         // V: 8 chunks per 64-elem row
    vrow[j] = rv; voff[j] = (cv ^ (rv & 7)) * 8;
  }
  const float skw = exp2f(sink[h] * 1.4426950408889634f);
  short8 onesf;
#pragma unroll
  for (int k = 0; k < 8; k++) onesf[k] = (short)0x3F80;
  int buf = 0;

  for (int pass = 0; pass < 2; ++pass) {
    const int qb = pass ? (int)blockIdx.x : (127 - (int)blockIdx.x);
    const int q0 = qb * 16;
    const int s_end = q0 + 16;
    const int nt = (s_end + 63) >> 6;

    short8 qf[6];
#pragma unroll
    for (int c = 0; c < 6; c++)
      qf[c] = *reinterpret_cast<const short8*>(
          q + (long)(q0 + lr) * (NH * HD) + h * HD + c * 32 + lg * 8);

    f32x4 acc[12], accS;
#pragma unroll
    for (int c = 0; c < 12; c++) acc[c] = f32x4{0.f, 0.f, 0.f, 0.f};
    accS = f32x4{0.f, 0.f, 0.f, 0.f};

    {
      char* dK = (char*)Ks[buf]; char* dV = (char*)Vs[buf];
#pragma unroll
      for (int j = 0; j < 3; j++)
        GLOAD16(kv + (long)krow[j] * HD + koff[j], dK + (tid + j * 512) * 16);
#pragma unroll
      for (int j = 0; j < 3; j++)
        GLOAD16(kvT + (long)vrow[j] * T_TOK + voff[j], dV + (tid + j * 512) * 16);
    }

    for (int t = 0; t < nt; ++t) {
      const int s0 = t * 64;
      const int sn = (t + 1 < nt) ? s0 + 64 : s0;
      {
        char* dK = (char*)Ks[buf ^ 1]; char* dV = (char*)Vs[buf ^ 1];
#pragma unroll
        for (int j = 0; j < 3; j++)
          GLOAD16(kv + (long)(sn + krow[j]) * HD + koff[j], dK + (tid + j * 512) * 16);
#pragma unroll
        for (int j = 0; j < 3; j++)
          GLOAD16(kvT + (long)vrow[j] * T_TOK + sn + voff[j], dV + (tid + j * 512) * 16);
      }
      asm volatile("s_waitcnt vmcnt(6)" ::: "memory");
      SCHEDB(); SBAR(); SCHEDB();

      const u16* Kb = Ks[buf];
      const u16* Vb = Vs[buf];
      f32x4 sc[4];
      __builtin_amdgcn_s_setprio(1);
#pragma unroll
      for (int sub = 0; sub < 4; sub++) {
        int c0 = s0 + sub * 16;
        f32x4 v = f32x4{0.f, 0.f, 0.f, 0.f};
        if (c0 < s_end) {
#pragma unroll
          for (int c = 0; c < 6; c++) {
            short8 kf = *reinterpret_cast<const short8*>(
                &Kb[((sub * 16 + lr) * HD + c * 32 + lg * 8) ^ ((lr & 7) << 3)]);
            v = __builtin_amdgcn_mfma_f32_16x16x32_bf16(qf[c], kf, v, 0, 0, 0);
          }
          int scol = c0 + lr;
#pragma unroll
          for (int i = 0; i < 4; i++) {
            int qrow = q0 + lg * 4 + i;
            v[i] = (scol <= qrow) ? v[i] : -__builtin_inff();
          }
        } else {
#pragma unroll
          for (int i = 0; i < 4; i++) v[i] = -__builtin_inff();
        }
        sc[sub] = v;
      }
      __builtin_amdgcn_s_setprio(0);

      float pr[4][4];
#pragma unroll
      for (int sub = 0; sub < 4; sub++)
#pragma unroll
        for (int i = 0; i < 4; i++) pr[sub][i] = exp2f(sc[sub][i]);
#pragma unroll
      for (int sub = 0; sub < 4; sub++)
#pragma unroll
        for (int i = 0; i < 4; i++)
          Pw[(lg * 4 + i) * 68 + sub * 16 + lr] = f2b(pr[sub][i]);
      short8 pf0 = *reinterpret_cast<const short8*>(&Pw[lr * 68 + lg * 8]);
      short8 pf1 = *reinterpret_cast<const short8*>(&Pw[lr * 68 + 32 + lg * 8]);

      __builtin_amdgcn_s_setprio(1);
#pragma unroll
      for (int c = 0; c < 12; c++) {
        short8 vf = *reinterpret_cast<const short8*>(
            &Vb[((c * 16 + lr) * 64 + lg * 8) ^ ((lr & 7) << 3)]);
        acc[c] = __builtin_amdgcn_mfma_f32_16x16x32_bf16(pf0, vf, acc[c], 0, 0, 0);
      }
      accS = __builtin_amdgcn_mfma_f32_16x16x32_bf16(pf0, onesf, accS, 0, 0, 0);
      if (s0 + 32 < s_end) {
#pragma unroll
        for (int c = 0; c < 12; c++) {
          short8 vf = *reinterpret_cast<const short8*>(
              &Vb[((c * 16 + lr) * 64 + 32 + lg * 8) ^ ((lr & 7) << 3)]);
          acc[c] = __builtin_amdgcn_mfma_f32_16x16x32_bf16(pf1, vf, acc[c], 0, 0, 0);
        }
        accS = __builtin_amdgcn_mfma_f32_16x16x32_bf16(pf1, onesf, accS, 0, 0, 0);
      }
      __builtin_amdgcn_s_setprio(0);

      SCHEDB(); SBAR(); SCHEDB();
      buf ^= 1;
    }

    asm volatile("s_waitcnt vmcnt(0)" ::: "memory");
    float rdenom[4];
#pragma unroll
    for (int i = 0; i < 4; i++) rdenom[i] = 1.0f / (skw + accS[i]);
#pragma unroll
    for (int c = 0; c < 12; c++)
#pragma unroll
      for (int i = 0; i < 4; i++) {
        int qrow = q0 + lg * 4 + i;
        out[(long)qrow * (NH * HD) + h * HD + c * 16 + lr] = f2b(acc[c][i] * rdenom[i]);
      }
    SBAR();
  }
}

// ---------------------------------------------------------------------------
extern "C" void kernel_launch(void* const* d_in, const int* in_sizes, int n_in,
                              void* d_out, int out_size, void* d_ws, size_t ws_size,
                              hipStream_t stream) {
  const float* x    = (const float*)d_in[0];
  const int* pos    = (const int*)d_in[1];
  const float* wq_a = (const float*)d_in[2];
  const float* q_nw = (const float*)d_in[3];
  const float* wq_b = (const float*)d_in[4];
  const float* wkv  = (const float*)d_in[5];
  const float* kvnw = (const float*)d_in[6];
  const float* sink = (const float*)d_in[7];
  const float* wo_a = (const float*)d_in[8];
  const float* wo_b = (const float*)d_in[9];
  const float* rcos = (const float*)d_in[10];
  const float* rsin = (const float*)d_in[11];
  float* y = (float*)d_out;

  char* ws = (char*)d_ws;
  size_t off = 0;
  auto alloc = [&](size_t bytes) -> void* {
    void* p = ws + off;
    off += (bytes + 255) & ~(size_t)255;
    return p;
  };
  u16* xb   = (u16*)alloc((size_t)T_TOK * HIDN * 2);
  u16* wqab = (u16*)alloc((size_t)QLORA * HIDN * 2);  // contiguous with wkvb:
  u16* wkvb = (u16*)alloc((size_t)HD * HIDN * 2);     // fused B = [wq_a; wkv]
  u16* wqbb = (u16*)alloc((size_t)NH * HD * QLORA * 2);
  u16* woab = (u16*)alloc((size_t)NG * OLORA * 1536 * 2);
  u16* wobb = (u16*)alloc((size_t)HIDN * NG * OLORA * 2);
  u16* t1f  = (u16*)alloc((size_t)T_TOK * NFUSE * 2);   // [2048][1728]
  u16* qn   = (u16*)alloc((size_t)T_TOK * NH * HD * 2);
  u16* kvb  = (u16*)alloc((size_t)T_TOK * HD * 2);
  u16* kvT  = (u16*)alloc((size_t)HD * T_TOK * 2);
  u16* ao   = (u16*)alloc((size_t)T_TOK * NH * HD * 2);
  u16* olow = (u16*)alloc((size_t)T_TOK * NG * OLORA * 2);

  hipLaunchKernelGGL(cast6, dim3(1024), dim3(256), 0, stream,
                     x,    xb,   (long)T_TOK * HIDN / 4,
                     wq_a, wqab, (long)QLORA * HIDN / 4,
                     wkv,  wkvb, (long)HD * HIDN / 4,
                     wq_b, wqbb, (long)NH * HD * QLORA / 4,
                     wo_a, woab, (long)NG * OLORA * 1536 / 4,
                     wo_b, wobb, (long)HIDN * NG * OLORA / 4);

  // fused GEMM1+GEMM3: t1f[2048,1728] = xb @ [wq_a; wkv]^T  (128^2 kernel)
  hipLaunchKernelGGL((gemm_bt<0>), dim3(16, 14, 1), dim3(256), 0, stream,
                     xb, wqab, (void*)t1f, 2048, NFUSE, 4096, 4096, 4096, NFUSE, 0L, 0L, 0L);
  hipLaunchKernelGGL(rmsnorm_kv, dim3(2048), dim3(256), 0, stream,
                     t1f, q_nw, kvb, kvT, kvnw, pos, rcos, rsin);
  // GEMM2: qn[2048,6144] = t1f[:, :1536] @ wq_b^T  (256^2 pipelined)
  hipLaunchKernelGGL((gemm256<0>), dim3(8, 24), dim3(512), 0, stream,
                     t1f, wqbb, (void*)qn, 6144, 1536, NFUSE, 1536, 6144);
  hipLaunchKernelGGL(qnorm_rope, dim3(2048, 8), dim3(256), 0, stream, qn, pos, rcos, rsin);
  // attention
  hipLaunchKernelGGL(attn, dim3(64, 4), dim3(512), 0, stream, qn, kvb, kvT, sink, ao);
  // GEMM4 (grouped): olow[2048, 4*512] = ao_g @ wo_a_g^T  (128^2 kernel)
  hipLaunchKernelGGL((gemm_bt<0>), dim3(16, 4, 4), dim3(256), 0, stream,
                     ao, woab, (void*)olow, 2048, 512, 1536, 6144, 1536, 2048,
                     1536L, (long)512 * 1536, 512L);
  // GEMM5: y[2048,4096] = olow @ wo_b^T (f32 out)  (256^2 pipelined)
  hipLaunchKernelGGL((gemm256<1>), dim3(8, 16), dim3(512), 0, stream,
                     olow, wobb, (void*)y, 4096, 2048, 2048, 2048, 4096);
}

// Round 15
// 372.154 us; speedup vs baseline: 1.3695x; 1.0441x over previous
//
#include <hip/hip_runtime.h>
#include <hip/hip_bf16.h>

#define T_TOK 2048
#define HIDN  4096
#define NH    32
#define HD    192
#define QLORA 1536
#define OLORA 512
#define NG    4
#define NFUSE 1728   // QLORA + HD (fused GEMM1+GEMM3 output width)

typedef unsigned short u16;
typedef __attribute__((ext_vector_type(8))) short short8;
typedef __attribute__((ext_vector_type(4))) short short4v;
typedef __attribute__((ext_vector_type(4))) float f32x4;

__device__ __forceinline__ float b2f(u16 u) {
  union { unsigned int u; float f; } x; x.u = ((unsigned int)u) << 16; return x.f;
}
__device__ __forceinline__ u16 f2b(float f) {
  union { float f; unsigned int u; } x; x.f = f;
  unsigned int r = x.u + 0x7fff + ((x.u >> 16) & 1);
  return (u16)(r >> 16);
}

#define GLOAD16(gp, lp) __builtin_amdgcn_global_load_lds( \
    (const __attribute__((address_space(1))) unsigned int*)(gp), \
    (__attribute__((address_space(3))) unsigned int*)(lp), 16, 0, 0)
#define SCHEDB() __builtin_amdgcn_sched_barrier(0)
#define SBAR()   __builtin_amdgcn_s_barrier()

// ---------------- fused cast f32 -> bf16 (6 segments, one launch) ----------
__device__ __forceinline__ void cast_seg(const float* __restrict__ src,
                                         u16* __restrict__ dst, long n4,
                                         long idx, long stride) {
  for (long j = idx; j < n4; j += stride) {
    float4 v = *reinterpret_cast<const float4*>(src + j * 4);
    short4v o;
    o[0] = (short)f2b(v.x); o[1] = (short)f2b(v.y);
    o[2] = (short)f2b(v.z); o[3] = (short)f2b(v.w);
    *reinterpret_cast<short4v*>(dst + j * 4) = o;
  }
}

__global__ __launch_bounds__(256)
void cast6(const float* s0, u16* d0, long n0, const float* s1, u16* d1, long n1,
           const float* s2, u16* d2, long n2, const float* s3, u16* d3, long n3,
           const float* s4, u16* d4, long n4c, const float* s5, u16* d5, long n5) {
  long idx = (long)blockIdx.x * blockDim.x + threadIdx.x;
  long stride = (long)gridDim.x * blockDim.x;
  cast_seg(s0, d0, n0, idx, stride);
  cast_seg(s1, d1, n1, idx, stride);
  cast_seg(s2, d2, n2, idx, stride);
  cast_seg(s3, d3, n3, idx, stride);
  cast_seg(s4, d4, n4c, idx, stride);
  cast_seg(s5, d5, n5, idx, stride);
}

// ---------------- GEMM: C[M,N] = A[M,K] * B[N,K]^T --------------------------
// 128x128 tile, BK=32, 4 waves. Double-buffered LDS, counted vmcnt(4),
// raw s_barrier, XCD-aware bijective block swizzle (nwg % 8 == 0).
// LDS chunk-slot swizzle by (row>>2)&3 (XOR, both stage-source and read):
// fragment ds_read_b128 goes 8-way -> 2-way (free) bank aliasing.
// OM: 0 = bf16 store, 1 = f32 store
template <int OM>
__global__ __launch_bounds__(256)
void gemm_bt(const u16* __restrict__ A, const u16* __restrict__ B,
             void* __restrict__ Cout, int M, int N, int K,
             int lda, int ldb, int ldc,
             long a_goff, long b_goff, long c_goff) {
  A += (long)blockIdx.z * a_goff;
  B += (long)blockIdx.z * b_goff;
  __shared__ u16 As[2][128 * 32];
  __shared__ u16 Bs[2][128 * 32];
  const int tid = threadIdx.x;
  const int lane = tid & 63;
  const int wave = tid >> 6;
  const int lg = lane >> 4, lr = lane & 15;
  const int wm = (wave >> 1) * 64, wn = (wave & 1) * 64;

  int bx = blockIdx.x, by = blockIdx.y;
  {
    int nx = gridDim.x, nwg = nx * gridDim.y;
    if ((nwg & 7) == 0) {
      int lin = by * nx + bx;
      int swz = (lin & 7) * (nwg >> 3) + (lin >> 3);
      bx = swz % nx; by = swz / nx;
    }
  }
  const int m0 = bx * 128, n0 = by * 128;

  // staging map: chunk c -> row c>>2, dest byte c*16 (linear);
  // SOURCE k-octet swizzled: ((c&3) ^ ((c>>4)&3)) * 8   [row>>2 = c>>4]
  const int i0 = tid, i1 = tid + 256;
  const int ra0 = i0 >> 2, ka0 = (((i0 & 3) ^ ((i0 >> 4) & 3))) * 8;
  const int ra1 = i1 >> 2, ka1 = (((i1 & 3) ^ ((i1 >> 4) & 3))) * 8;
  const u16* pA0 = A + (long)(m0 + ra0) * lda + ka0;
  const u16* pA1 = A + (long)(m0 + ra1) * lda + ka1;
  int rb0 = n0 + ra0; if (rb0 > N - 1) rb0 = N - 1;
  int rb1 = n0 + ra1; if (rb1 > N - 1) rb1 = N - 1;
  const u16* pB0 = B + (long)rb0 * ldb + ka0;
  const u16* pB1 = B + (long)rb1 * ldb + ka1;
  const int woff = wave * 1024;

  // read-side swizzled slot (u16 offset), wave-constant:
  // row = wm|wn + i*16 + lr -> (row>>2)&3 = (lr>>2)&3
  const int sa = (lg ^ ((lr >> 2) & 3)) * 8;

  f32x4 acc[4][4];
#pragma unroll
  for (int a = 0; a < 4; a++)
#pragma unroll
    for (int b = 0; b < 4; b++) acc[a][b] = f32x4{0.f, 0.f, 0.f, 0.f};

  GLOAD16(pA0, (char*)As + woff);
  GLOAD16(pA1, (char*)As + 4096 + woff);
  GLOAD16(pB0, (char*)Bs + woff);
  GLOAD16(pB1, (char*)Bs + 4096 + woff);

  const int nk = K >> 5;
  int buf = 0;
  for (int kk = 0; kk < nk; ++kk) {
    const int kn = (kk + 1 < nk) ? (kk + 1) * 32 : kk * 32;
    {
      char* dA = (char*)As + (buf ^ 1) * 8192 + woff;
      char* dB = (char*)Bs + (buf ^ 1) * 8192 + woff;
      GLOAD16(pA0 + kn, dA);
      GLOAD16(pA1 + kn, dA + 4096);
      GLOAD16(pB0 + kn, dB);
      GLOAD16(pB1 + kn, dB + 4096);
    }
    asm volatile("s_waitcnt vmcnt(4)" ::: "memory");  // current tile resident
    SCHEDB(); SBAR(); SCHEDB();

    short8 af[4], bf[4];
#pragma unroll
    for (int i = 0; i < 4; i++)
      af[i] = *reinterpret_cast<const short8*>(&As[buf][(wm + i * 16 + lr) * 32 + sa]);
#pragma unroll
    for (int i = 0; i < 4; i++)
      bf[i] = *reinterpret_cast<const short8*>(&Bs[buf][(wn + i * 16 + lr) * 32 + sa]);
#pragma unroll
    for (int mi = 0; mi < 4; mi++)
#pragma unroll
      for (int ni = 0; ni < 4; ni++)
        acc[mi][ni] = __builtin_amdgcn_mfma_f32_16x16x32_bf16(af[mi], bf[ni], acc[mi][ni], 0, 0, 0);

    SCHEDB(); SBAR(); SCHEDB();   // all waves done reading buf
    buf ^= 1;
  }
  asm volatile("s_waitcnt vmcnt(0)" ::: "memory");  // drain dup stage

  const long cbase = (long)blockIdx.z * c_goff;
#pragma unroll
  for (int mi = 0; mi < 4; mi++) {
#pragma unroll
    for (int ni = 0; ni < 4; ni++) {
      int col = n0 + wn + ni * 16 + lr;
      if (col < N) {
#pragma unroll
        for (int i = 0; i < 4; i++) {
          int row = m0 + wm + mi * 16 + lg * 4 + i;
          float v = acc[mi][ni][i];
          if constexpr (OM == 0)
            reinterpret_cast<u16*>(Cout)[cbase + (long)row * ldc + col] = f2b(v);
          else
            reinterpret_cast<float*>(Cout)[cbase + (long)row * ldc + col] = v;
        }
      }
    }
  }
}

// ---------------- fused RMSNorm(first 1536 cols) + kv-norm+RoPE ------------
__global__ __launch_bounds__(256)
void rmsnorm_kv(u16* __restrict__ buf, const float* __restrict__ w,
                u16* __restrict__ kvb, u16* __restrict__ kvT,
                const float* __restrict__ kvnw, const int* __restrict__ pos,
                const float* __restrict__ rc, const float* __restrict__ rs) {
  const int row = blockIdx.x;
  u16* p = buf + (long)row * NFUSE;
  const int tid = threadIdx.x;
  float v[6];
  float ss = 0.f;
#pragma unroll
  for (int j = 0; j < 6; j++) { v[j] = b2f(p[tid + j * 256]); ss += v[j] * v[j]; }
#pragma unroll
  for (int m = 1; m < 64; m <<= 1) ss += __shfl_xor(ss, m);
  __shared__ float red[4];
  if ((tid & 63) == 0) red[tid >> 6] = ss;
  __syncthreads();
  ss = red[0] + red[1] + red[2] + red[3];
  float rinv = rsqrtf(ss * (1.0f / QLORA) + 1e-6f);
#pragma unroll
  for (int j = 0; j < 6; j++) p[tid + j * 256] = f2b(v[j] * rinv * w[tid + j * 256]);

  if (tid < 64) {  // wave 0: kv tail norm + rope
    const u16* src = p + QLORA;
    const int lane = tid;
    float v0 = b2f(src[lane]), v1 = b2f(src[lane + 64]), v2 = b2f(src[lane + 128]);
    float s2 = v0 * v0 + v1 * v1 + v2 * v2;
#pragma unroll
    for (int m = 1; m < 64; m <<= 1) s2 += __shfl_xor(s2, m);
    float ri = rsqrtf(s2 * (1.0f / HD) + 1e-6f);
    v0 *= ri * kvnw[lane]; v1 *= ri * kvnw[lane + 64]; v2 *= ri * kvnw[lane + 128];
    float partner = __shfl_xor(v2, 1);
    int pp = pos[row];
    int j = lane >> 1;
    float c = rc[pp * 32 + j], s = rs[pp * 32 + j];
    float r = ((lane & 1) == 0) ? (v2 * c - partner * s) : (partner * s + v2 * c);
    u16 o0 = f2b(v0), o1 = f2b(v1), o2 = f2b(r);
    u16* kp = kvb + (long)row * HD;
    kp[lane] = o0; kp[lane + 64] = o1; kp[lane + 128] = o2;
    kvT[(long)lane * T_TOK + row] = o0;
    kvT[(long)(lane + 64) * T_TOK + row] = o1;
    kvT[(long)(lane + 128) * T_TOK + row] = o2;
  }
}

// ---------------- per-(t,h) RMSNorm (unweighted) + RoPE, in-place ----------
// Output pre-scaled by 192^-0.5 * log2(e): attention runs in exp2 domain.
__global__ __launch_bounds__(256)
void qnorm_rope(u16* __restrict__ q, const int* __restrict__ pos,
                const float* __restrict__ rc, const float* __restrict__ rs) {
  const int t = blockIdx.x, h = blockIdx.y * 4 + (threadIdx.x >> 6);
  u16* p = q + (long)t * (NH * HD) + h * HD;
  const int lane = threadIdx.x & 63;
  const float QS = 0.07216878364870323f * 1.4426950408889634f;
  float v0 = b2f(p[lane]), v1 = b2f(p[lane + 64]), v2 = b2f(p[lane + 128]);
  float ss = v0 * v0 + v1 * v1 + v2 * v2;
#pragma unroll
  for (int m = 1; m < 64; m <<= 1) ss += __shfl_xor(ss, m);
  float rinv = rsqrtf(ss * (1.0f / HD) + 1e-6f);
  v0 *= rinv; v1 *= rinv; v2 *= rinv;
  float partner = __shfl_xor(v2, 1);
  int pp = pos[t];
  int j = lane >> 1;
  float c = rc[pp * 32 + j], s = rs[pp * 32 + j];
  float r = ((lane & 1) == 0) ? (v2 * c - partner * s) : (partner * s + v2 * c);
  p[lane] = f2b(v0 * QS); p[lane + 64] = f2b(v1 * QS); p[lane + 128] = f2b(r * QS);
}

// ---------------- flash attention (R10 structure, reduction-free softmax) --
// block = 512 thr = 8 waves = 8 heads x same 16 q rows. KVBLK=64.
// Double-buffered K/V tiles, counted vmcnt(6), raw barriers. Each block
// processes two q-tiles (127-bx, bx) -> uniform work; grid 64 x 4 = 256.
__global__ __launch_bounds__(512)
void attn(const u16* __restrict__ q, const u16* __restrict__ kv,
          const u16* __restrict__ kvT, const float* __restrict__ sink,
          u16* __restrict__ out) {
  __shared__ u16 Ks[2][64 * 192];   // 48 KB
  __shared__ u16 Vs[2][192 * 64];   // 48 KB
  __shared__ u16 P[8][16 * 68];     // 17 KB, per-wave private
  const int tid = threadIdx.x;
  const int wave = tid >> 6, lane = tid & 63;
  const int lg = lane >> 4, lr = lane & 15;
  const int h = blockIdx.y * 8 + wave;
  u16* Pw = P[wave];

  int krow[3], koff[3], vrow[3], voff[3];
#pragma unroll
  for (int j = 0; j < 3; j++) {
    int s = tid + j * 512;
    int rk = s / 24, ck = s - rk * 24;   // K: 24 chunks per 192-elem row
    krow[j] = rk; koff[j] = (ck ^ (rk & 7)) * 8;
    int rv = s >> 3, cv = s & 7;         // V: 8 chunks per 64-elem row
    vrow[j] = rv; voff[j] = (cv ^ (rv & 7)) * 8;
  }
  const float skw = exp2f(sink[h] * 1.4426950408889634f);
  short8 onesf;
#pragma unroll
  for (int k = 0; k < 8; k++) onesf[k] = (short)0x3F80;
  int buf = 0;

  for (int pass = 0; pass < 2; ++pass) {
    const int qb = pass ? (int)blockIdx.x : (127 - (int)blockIdx.x);
    const int q0 = qb * 16;
    const int s_end = q0 + 16;
    const int nt = (s_end + 63) >> 6;

    short8 qf[6];
#pragma unroll
    for (int c = 0; c < 6; c++)
      qf[c] = *reinterpret_cast<const short8*>(
          q + (long)(q0 + lr) * (NH * HD) + h * HD + c * 32 + lg * 8);

    f32x4 acc[12], accS;
#pragma unroll
    for (int c = 0; c < 12; c++) acc[c] = f32x4{0.f, 0.f, 0.f, 0.f};
    accS = f32x4{0.f, 0.f, 0.f, 0.f};

    {
      char* dK = (char*)Ks[buf]; char* dV = (char*)Vs[buf];
#pragma unroll
      for (int j = 0; j < 3; j++)
        GLOAD16(kv + (long)krow[j] * HD + koff[j], dK + (tid + j * 512) * 16);
#pragma unroll
      for (int j = 0; j < 3; j++)
        GLOAD16(kvT + (long)vrow[j] * T_TOK + voff[j], dV + (tid + j * 512) * 16);
    }

    for (int t = 0; t < nt; ++t) {
      const int s0 = t * 64;
      const int sn = (t + 1 < nt) ? s0 + 64 : s0;
      {
        char* dK = (char*)Ks[buf ^ 1]; char* dV = (char*)Vs[buf ^ 1];
#pragma unroll
        for (int j = 0; j < 3; j++)
          GLOAD16(kv + (long)(sn + krow[j]) * HD + koff[j], dK + (tid + j * 512) * 16);
#pragma unroll
        for (int j = 0; j < 3; j++)
          GLOAD16(kvT + (long)vrow[j] * T_TOK + sn + voff[j], dV + (tid + j * 512) * 16);
      }
      asm volatile("s_waitcnt vmcnt(6)" ::: "memory");
      SCHEDB(); SBAR(); SCHEDB();

      const u16* Kb = Ks[buf];
      const u16* Vb = Vs[buf];
      f32x4 sc[4];
      __builtin_amdgcn_s_setprio(1);
#pragma unroll
      for (int sub = 0; sub < 4; sub++) {
        int c0 = s0 + sub * 16;
        f32x4 v = f32x4{0.f, 0.f, 0.f, 0.f};
        if (c0 < s_end) {
#pragma unroll
          for (int c = 0; c < 6; c++) {
            short8 kf = *reinterpret_cast<const short8*>(
                &Kb[((sub * 16 + lr) * HD + c * 32 + lg * 8) ^ ((lr & 7) << 3)]);
            v = __builtin_amdgcn_mfma_f32_16x16x32_bf16(qf[c], kf, v, 0, 0, 0);
          }
          int scol = c0 + lr;
#pragma unroll
          for (int i = 0; i < 4; i++) {
            int qrow = q0 + lg * 4 + i;
            v[i] = (scol <= qrow) ? v[i] : -__builtin_inff();
          }
        } else {
#pragma unroll
          for (int i = 0; i < 4; i++) v[i] = -__builtin_inff();
        }
        sc[sub] = v;
      }
      __builtin_amdgcn_s_setprio(0);

      float pr[4][4];
#pragma unroll
      for (int sub = 0; sub < 4; sub++)
#pragma unroll
        for (int i = 0; i < 4; i++) pr[sub][i] = exp2f(sc[sub][i]);
#pragma unroll
      for (int sub = 0; sub < 4; sub++)
#pragma unroll
        for (int i = 0; i < 4; i++)
          Pw[(lg * 4 + i) * 68 + sub * 16 + lr] = f2b(pr[sub][i]);
      short8 pf0 = *reinterpret_cast<const short8*>(&Pw[lr * 68 + lg * 8]);
      short8 pf1 = *reinterpret_cast<const short8*>(&Pw[lr * 68 + 32 + lg * 8]);

      __builtin_amdgcn_s_setprio(1);
#pragma unroll
      for (int c = 0; c < 12; c++) {
        short8 vf = *reinterpret_cast<const short8*>(
            &Vb[((c * 16 + lr) * 64 + lg * 8) ^ ((lr & 7) << 3)]);
        acc[c] = __builtin_amdgcn_mfma_f32_16x16x32_bf16(pf0, vf, acc[c], 0, 0, 0);
      }
      accS = __builtin_amdgcn_mfma_f32_16x16x32_bf16(pf0, onesf, accS, 0, 0, 0);
      if (s0 + 32 < s_end) {
#pragma unroll
        for (int c = 0; c < 12; c++) {
          short8 vf = *reinterpret_cast<const short8*>(
              &Vb[((c * 16 + lr) * 64 + 32 + lg * 8) ^ ((lr & 7) << 3)]);
          acc[c] = __builtin_amdgcn_mfma_f32_16x16x32_bf16(pf1, vf, acc[c], 0, 0, 0);
        }
        accS = __builtin_amdgcn_mfma_f32_16x16x32_bf16(pf1, onesf, accS, 0, 0, 0);
      }
      __builtin_amdgcn_s_setprio(0);

      SCHEDB(); SBAR(); SCHEDB();
      buf ^= 1;
    }

    asm volatile("s_waitcnt vmcnt(0)" ::: "memory");
    float rdenom[4];
#pragma unroll
    for (int i = 0; i < 4; i++) rdenom[i] = 1.0f / (skw + accS[i]);
#pragma unroll
    for (int c = 0; c < 12; c++)
#pragma unroll
      for (int i = 0; i < 4; i++) {
        int qrow = q0 + lg * 4 + i;
        out[(long)qrow * (NH * HD) + h * HD + c * 16 + lr] = f2b(acc[c][i] * rdenom[i]);
      }
    SBAR();
  }
}

// ---------------------------------------------------------------------------
extern "C" void kernel_launch(void* const* d_in, const int* in_sizes, int n_in,
                              void* d_out, int out_size, void* d_ws, size_t ws_size,
                              hipStream_t stream) {
  const float* x    = (const float*)d_in[0];
  const int* pos    = (const int*)d_in[1];
  const float* wq_a = (const float*)d_in[2];
  const float* q_nw = (const float*)d_in[3];
  const float* wq_b = (const float*)d_in[4];
  const float* wkv  = (const float*)d_in[5];
  const float* kvnw = (const float*)d_in[6];
  const float* sink = (const float*)d_in[7];
  const float* wo_a = (const float*)d_in[8];
  const float* wo_b = (const float*)d_in[9];
  const float* rcos = (const float*)d_in[10];
  const float* rsin = (const float*)d_in[11];
  float* y = (float*)d_out;

  char* ws = (char*)d_ws;
  size_t off = 0;
  auto alloc = [&](size_t bytes) -> void* {
    void* p = ws + off;
    off += (bytes + 255) & ~(size_t)255;
    return p;
  };
  u16* xb   = (u16*)alloc((size_t)T_TOK * HIDN * 2);
  u16* wqab = (u16*)alloc((size_t)QLORA * HIDN * 2);  // contiguous with wkvb:
  u16* wkvb = (u16*)alloc((size_t)HD * HIDN * 2);     // fused B = [wq_a; wkv]
  u16* wqbb = (u16*)alloc((size_t)NH * HD * QLORA * 2);
  u16* woab = (u16*)alloc((size_t)NG * OLORA * 1536 * 2);
  u16* wobb = (u16*)alloc((size_t)HIDN * NG * OLORA * 2);
  u16* t1f  = (u16*)alloc((size_t)T_TOK * NFUSE * 2);   // [2048][1728]
  u16* qn   = (u16*)alloc((size_t)T_TOK * NH * HD * 2);
  u16* kvb  = (u16*)alloc((size_t)T_TOK * HD * 2);
  u16* kvT  = (u16*)alloc((size_t)HD * T_TOK * 2);
  u16* ao   = (u16*)alloc((size_t)T_TOK * NH * HD * 2);
  u16* olow = (u16*)alloc((size_t)T_TOK * NG * OLORA * 2);

  hipLaunchKernelGGL(cast6, dim3(1024), dim3(256), 0, stream,
                     x,    xb,   (long)T_TOK * HIDN / 4,
                     wq_a, wqab, (long)QLORA * HIDN / 4,
                     wkv,  wkvb, (long)HD * HIDN / 4,
                     wq_b, wqbb, (long)NH * HD * QLORA / 4,
                     wo_a, woab, (long)NG * OLORA * 1536 / 4,
                     wo_b, wobb, (long)HIDN * NG * OLORA / 4);

  // fused GEMM1+GEMM3: t1f[2048,1728] = xb @ [wq_a; wkv]^T
  hipLaunchKernelGGL((gemm_bt<0>), dim3(16, 14, 1), dim3(256), 0, stream,
                     xb, wqab, (void*)t1f, 2048, NFUSE, 4096, 4096, 4096, NFUSE, 0L, 0L, 0L);
  hipLaunchKernelGGL(rmsnorm_kv, dim3(2048), dim3(256), 0, stream,
                     t1f, q_nw, kvb, kvT, kvnw, pos, rcos, rsin);
  // GEMM2: qn[2048,6144] = t1f[:, :1536] @ wq_b^T
  hipLaunchKernelGGL((gemm_bt<0>), dim3(16, 48, 1), dim3(256), 0, stream,
                     t1f, wqbb, (void*)qn, 2048, 6144, 1536, NFUSE, 1536, 6144, 0L, 0L, 0L);
  hipLaunchKernelGGL(qnorm_rope, dim3(2048, 8), dim3(256), 0, stream, qn, pos, rcos, rsin);
  // attention: 64 paired q-tiles x 4 head-groups = 256 blocks, 512 thr
  hipLaunchKernelGGL(attn, dim3(64, 4), dim3(512), 0, stream, qn, kvb, kvT, sink, ao);
  // GEMM4 (grouped): olow[2048, 4*512] = ao_g @ wo_a_g^T
  hipLaunchKernelGGL((gemm_bt<0>), dim3(16, 4, 4), dim3(256), 0, stream,
                     ao, woab, (void*)olow, 2048, 512, 1536, 6144, 1536, 2048,
                     1536L, (long)512 * 1536, 512L);
  // GEMM5: y[2048,4096] = olow @ wo_b^T (f32 out)
  hipLaunchKernelGGL((gemm_bt<1>), dim3(16, 32, 1), dim3(256), 0, stream,
                     olow, wobb, (void*)y, 2048, 4096, 2048, 2048, 2048, 4096, 0L, 0L, 0L);
}